// Round 5
// baseline (797.263 us; speedup 1.0000x reference)
//
#include <hip/hip_runtime.h>
#include <hip/hip_bf16.h>
#include <stdint.h>

typedef unsigned short u16;
typedef __attribute__((ext_vector_type(8))) short short8;
typedef __attribute__((ext_vector_type(4))) short s4v;
typedef __attribute__((ext_vector_type(4))) float f32x4;

__device__ inline u16 f2bf(float f) {
    union { float f; unsigned int u; } x; x.f = f;
    unsigned int u = x.u;
    unsigned int r = (u + 0x7FFFu + ((u >> 16) & 1u)) >> 16;
    return (u16)r;
}

// 16x16x16 bf16 MFMA: prefer intrinsics (compiler-managed hazards); asm fallback carries
// explicit s_nop fences.
#if __has_builtin(__builtin_amdgcn_mfma_f32_16x16x16bf16_1k)
#define MFMA16(a, b, c) __builtin_amdgcn_mfma_f32_16x16x16bf16_1k((a), (b), (c), 0, 0, 0)
#elif __has_builtin(__builtin_amdgcn_mfma_f32_16x16x16_bf16)
#define MFMA16(a, b, c) __builtin_amdgcn_mfma_f32_16x16x16_bf16((a), (b), (c), 0, 0, 0)
#else
__device__ inline f32x4 mfma16_asm(s4v a, s4v b, f32x4 c) {
    asm volatile("s_nop 1\n\tv_mfma_f32_16x16x16_bf16 %0, %1, %2, %0\n\ts_nop 7\n\ts_nop 7"
                 : "+v"(c) : "v"(a), "v"(b));
    return c;
}
#define MFMA16(a, b, c) mfma16_asm((a), (b), (c))
#endif

// ---------------- prepass: convert x + weights to bf16, 8 elems/thread ----------------
#define NX8 4816896   // 100352*384/8
#define NQ8 55296     // 1152*384/8
#define NP8 18432     // 384*384/8
__global__ __launch_bounds__(256) void prep_all(const float* __restrict__ x,
                                                const float* __restrict__ qw,
                                                const float* __restrict__ pw,
                                                u16* __restrict__ xb,
                                                u16* __restrict__ wq,
                                                u16* __restrict__ wp) {
    size_t i = (size_t)blockIdx.x * 256 + threadIdx.x;
    const float* src; u16* dst; size_t off;
    if (i < NX8)            { src = x;  dst = xb; off = i; }
    else if (i < NX8 + NQ8) { src = qw; dst = wq; off = i - NX8; }
    else                    { src = pw; dst = wp; off = i - (NX8 + NQ8); }
    float4 v0 = ((const float4*)src)[off * 2];
    float4 v1 = ((const float4*)src)[off * 2 + 1];
    u16 h[8];
    h[0] = f2bf(v0.x); h[1] = f2bf(v0.y); h[2] = f2bf(v0.z); h[3] = f2bf(v0.w);
    h[4] = f2bf(v1.x); h[5] = f2bf(v1.y); h[6] = f2bf(v1.z); h[7] = f2bf(v1.w);
    *(uint4*)(dst + off * 8) = *(const uint4*)h;
}

// ---------------- kernel 1: QKV GEMM -- LDS-FREE, barrier-free, reg-pipelined --------
// C[m,n] = sum_k xb[m,k]*wq[n,k] + b[n]; M=100352, N=1152, K=384, BK=32, 12 K-steps.
// Operand panels are L2-resident (wq = 864KB total; live A panels ~1.7MB/XCD via the
// XCD swizzle), and the MFMA fragment = "8 contig bf16 at row base+lc, col k0+lr*8"
// = 16 rows x 64B segments per wave-load -- the direct-from-global idiom proven in
// attn_kernel. So: no LDS staging at all. No barriers, no vmcnt(0) drains, no bank
// conflicts; fragments are prefetched one K-step ahead into named registers (static
// indexing, no scratch). Waves are fully independent -> pure ILP+TLP.
__global__ __launch_bounds__(256, 3) void qkv_gemm(const u16* __restrict__ xb,
                                                   const u16* __restrict__ wq,
                                                   const float* __restrict__ bias,
                                                   u16* __restrict__ qkv_out) {
    const int tid = threadIdx.x;
    const int wave = tid >> 6, lane = tid & 63;
    const int lr = lane >> 4, lc = lane & 15;
    const int wm = (wave & 1) * 64, wn = (wave >> 1) * 64;
    const int lin = blockIdx.x;
    const int xcd = lin & 7;
    const int idx = lin >> 3;            // 0..881
    const int nBase = (idx % 9) * 128;
    const int mBase = (xcd * 98 + idx / 9) * 128;

    f32x4 acc[4][4] = {};

    // fragment base pointers: row (mBase+wm+i*16+lc), col (k0 + lr*8)
    const u16* aP = xb + (size_t)(mBase + wm + lc) * 384 + lr * 8;
    const u16* bP = wq + (size_t)(nBase + wn + lc) * 384 + lr * 8;

    short8 aC[4], bC[4], aN[4], bN[4];
#pragma unroll
    for (int i = 0; i < 4; ++i) {
        aC[i] = *(const short8*)(aP + (size_t)i * 16 * 384);
        bC[i] = *(const short8*)(bP + (size_t)i * 16 * 384);
    }
#pragma unroll
    for (int t = 0; t < 12; ++t) {
        if (t < 11) {
            const int k0 = (t + 1) * 32;
#pragma unroll
            for (int i = 0; i < 4; ++i) {
                aN[i] = *(const short8*)(aP + (size_t)i * 16 * 384 + k0);
                bN[i] = *(const short8*)(bP + (size_t)i * 16 * 384 + k0);
            }
        }
#pragma unroll
        for (int i = 0; i < 4; ++i)
#pragma unroll
            for (int j = 0; j < 4; ++j)
                acc[i][j] = __builtin_amdgcn_mfma_f32_16x16x32_bf16(bC[j], aC[i], acc[i][j], 0, 0, 0);
        if (t < 11) {
#pragma unroll
            for (int i = 0; i < 4; ++i) { aC[i] = aN[i]; bC[i] = bN[i]; }
        }
    }

    // epilogue: swapped-C mapping: m = wm+i*16+lc (lane), n = wn+j*16+lr*4+r (reg)
    const float scale = 0.17677669529663687f;  // 32^-0.5
#pragma unroll
    for (int j = 0; j < 4; ++j) {
        int gnb = nBase + wn + j * 16 + lr * 4;
        float4 bv = *(const float4*)&bias[gnb];
        float mult = (gnb < 384) ? scale : 1.0f;   // q-section; group of 4 never straddles
#pragma unroll
        for (int i = 0; i < 4; ++i) {
            int gm = mBase + wm + i * 16 + lc;
            union { u16 h[4]; uint2 u; } pk;
            pk.h[0] = f2bf((acc[i][j][0] + bv.x) * mult);
            pk.h[1] = f2bf((acc[i][j][1] + bv.y) * mult);
            pk.h[2] = f2bf((acc[i][j][2] + bv.z) * mult);
            pk.h[3] = f2bf((acc[i][j][3] + bv.w) * mult);
            *(uint2*)(qkv_out + (size_t)gm * 1152 + gnb) = pk.u;
        }
    }
}

// ---------------- kernel 2: windowed attention (verified round-3 version) ----------
__global__ __launch_bounds__(256, 3) void attn_kernel(const u16* __restrict__ qkv,
                                                      const float* __restrict__ mask,
                                                      u16* __restrict__ aout) {
#define PST 68  // Vt LDS row stride (bf16 elems)
    __shared__ u16 Vt_s[4][32 * PST];
    const int tid = threadIdx.x;
    const int wave = tid >> 6, lane = tid & 63;
    const int lr = lane >> 4, lc = lane & 15;
    const int bid = blockIdx.x;
    const int b = bid / 3;
    const int h = (bid - b * 3) * 4 + wave;
    const int w = b & 63;
    const float* mrow = mask + (size_t)w * 2401;

    const u16* Q = qkv + (size_t)b * 49 * 1152 + h * 32;
    const u16* K = Q + 384;
    const u16* V = Q + 768;

    // stage V transposed: Vt[d][j], zero-padded j>=49
    {
        u16 vv[32];
        if (lane < 49) {
#pragma unroll
            for (int c = 0; c < 4; ++c)
                *(uint4*)&vv[c * 8] = *(const uint4*)(V + (size_t)lane * 1152 + c * 8);
        } else {
#pragma unroll
            for (int c = 0; c < 32; ++c) vv[c] = 0;
        }
#pragma unroll
        for (int d = 0; d < 32; ++d)
            Vt_s[wave][d * PST + lane] = vv[d];
    }

    // Q/K fragments straight from global (16B contiguous per lane, row stride 1152)
    short8 qf[4], kf[4];
    const short8 z8 = {0, 0, 0, 0, 0, 0, 0, 0};
#pragma unroll
    for (int i = 0; i < 4; ++i) {
        int row = i * 16 + lc;
        qf[i] = (row < 49) ? *(const short8*)(Q + (size_t)row * 1152 + lr * 8) : z8;
        kf[i] = (row < 49) ? *(const short8*)(K + (size_t)row * 1152 + lr * 8) : z8;
    }

    __syncthreads();   // Vt_s writes -> vfA reads

    // Vt A-frags for 16x16x16: lane (lr,lc) holds Vt[d=nt*16+lc][k=sj*16+lr*4 .. +3]
    s4v vfA[2][4];
#pragma unroll
    for (int nt = 0; nt < 2; ++nt)
#pragma unroll
        for (int sj = 0; sj < 4; ++sj)
            vfA[nt][sj] = *(const s4v*)&Vt_s[wave][(nt * 16 + lc) * PST + sj * 16 + lr * 4];

    // S2 = K Q^T (swapped): tile (si,sj): rows k (reg), cols q (lane)
    f32x4 S2[4][4] = {};
#pragma unroll
    for (int si = 0; si < 4; ++si)
#pragma unroll
        for (int sj = 0; sj < 4; ++sj)
            S2[si][sj] = __builtin_amdgcn_mfma_f32_16x16x32_bf16(kf[sj], qf[si], S2[si][sj], 0, 0, 0);

    // per-q-tile: softmax (in-register) -> P-frag pack -> PV -> store
    const size_t orow = (size_t)b * 49 * 384 + h * 32 + lr * 4;
#pragma unroll
    for (int si = 0; si < 4; ++si) {
        int q = si * 16 + lc;
        int im = (q < 49) ? q : 48;       // clamped; padded q never stored
        const float* mq = mrow + im * 49;
        float s = 0.0f;
        s4v pfq[4];
#pragma unroll
        for (int sj = 0; sj < 4; ++sj) {
            int kbase = sj * 16 + lr * 4;
            s4v pk;
#pragma unroll
            for (int r = 0; r < 4; ++r) {
                int k = kbase + r;
                float t = (k < 49) ? (S2[si][sj][r] + mq[k]) : -1e30f;
                float p = __expf(t);      // exp(-1e30) = 0: padded k contributes nothing
                s += p;
                pk[r] = (short)f2bf(p);
            }
            pfq[sj] = pk;
        }
        // complete k-sum: other k-chunks live on lanes differing in lr (bits 4,5)
        s += __shfl_xor(s, 16);
        s += __shfl_xor(s, 32);

        f32x4 O0 = {}, O1 = {};
#pragma unroll
        for (int sj = 0; sj < 4; ++sj) {
            O0 = MFMA16(vfA[0][sj], pfq[sj], O0);
            O1 = MFMA16(vfA[1][sj], pfq[sj], O1);
        }

        if (q < 49) {
            float rl = __builtin_amdgcn_rcpf(s);
            union { u16 h[4]; uint2 u; } pk;
            pk.h[0] = f2bf(O0[0] * rl); pk.h[1] = f2bf(O0[1] * rl);
            pk.h[2] = f2bf(O0[2] * rl); pk.h[3] = f2bf(O0[3] * rl);
            *(uint2*)(aout + orow + (size_t)q * 384) = pk.u;
            pk.h[0] = f2bf(O1[0] * rl); pk.h[1] = f2bf(O1[1] * rl);
            pk.h[2] = f2bf(O1[2] * rl); pk.h[3] = f2bf(O1[3] * rl);
            *(uint2*)(aout + orow + (size_t)q * 384 + 16) = pk.u;
        }
    }
#undef PST
}

// ---------------- kernel 3: proj GEMM -- LDS-free, barrier-free (same as qkv) --------
// out[m,n] = sum_k a[m,k]*wp[n,k] + b[n]; fp32 out. M=100352, N=384, K=384.
__global__ __launch_bounds__(256, 3) void proj_gemm(const u16* __restrict__ a,
                                                    const u16* __restrict__ wp,
                                                    const float* __restrict__ bias,
                                                    float* __restrict__ out) {
    const int tid = threadIdx.x;
    const int wave = tid >> 6, lane = tid & 63;
    const int lr = lane >> 4, lc = lane & 15;
    const int wm = (wave & 1) * 64, wn = (wave >> 1) * 64;
    const int lin = blockIdx.x;
    const int xcd = lin & 7;
    const int idx = lin >> 3;            // 0..293
    const int nBase = (idx % 3) * 128;
    const int mBase = (xcd * 98 + idx / 3) * 128;

    f32x4 acc[4][4] = {};

    const u16* aP = a  + (size_t)(mBase + wm + lc) * 384 + lr * 8;
    const u16* bP = wp + (size_t)(nBase + wn + lc) * 384 + lr * 8;

    short8 aC[4], bC[4], aN[4], bN[4];
#pragma unroll
    for (int i = 0; i < 4; ++i) {
        aC[i] = *(const short8*)(aP + (size_t)i * 16 * 384);
        bC[i] = *(const short8*)(bP + (size_t)i * 16 * 384);
    }
#pragma unroll
    for (int t = 0; t < 12; ++t) {
        if (t < 11) {
            const int k0 = (t + 1) * 32;
#pragma unroll
            for (int i = 0; i < 4; ++i) {
                aN[i] = *(const short8*)(aP + (size_t)i * 16 * 384 + k0);
                bN[i] = *(const short8*)(bP + (size_t)i * 16 * 384 + k0);
            }
        }
#pragma unroll
        for (int i = 0; i < 4; ++i)
#pragma unroll
            for (int j = 0; j < 4; ++j)
                acc[i][j] = __builtin_amdgcn_mfma_f32_16x16x32_bf16(bC[j], aC[i], acc[i][j], 0, 0, 0);
        if (t < 11) {
#pragma unroll
            for (int i = 0; i < 4; ++i) { aC[i] = aN[i]; bC[i] = bN[i]; }
        }
    }

    // epilogue: swapped-C mapping: m = wm+i*16+lc (lane), n = wn+j*16+lr*4+r (reg)
#pragma unroll
    for (int j = 0; j < 4; ++j) {
        int gnb = nBase + wn + j * 16 + lr * 4;
        float4 bv = *(const float4*)&bias[gnb];
#pragma unroll
        for (int i = 0; i < 4; ++i) {
            int gm = mBase + wm + i * 16 + lc;
            float4 o;
            o.x = acc[i][j][0] + bv.x;
            o.y = acc[i][j][1] + bv.y;
            o.z = acc[i][j][2] + bv.z;
            o.w = acc[i][j][3] + bv.w;
            *(float4*)(out + (size_t)gm * 384 + gnb) = o;
        }
    }
}

// ---------------- launch ----------------
extern "C" void kernel_launch(void* const* d_in, const int* in_sizes, int n_in,
                              void* d_out, int out_size, void* d_ws, size_t ws_size,
                              hipStream_t stream) {
    const float* x      = (const float*)d_in[0];
    const float* mask   = (const float*)d_in[1];
    const float* qkv_w  = (const float*)d_in[2];
    const float* qkv_b  = (const float*)d_in[3];
    const float* proj_w = (const float*)d_in[4];
    const float* proj_b = (const float*)d_in[5];
    float* out = (float*)d_out;

    char* ws = (char*)d_ws;
    u16* wq   = (u16*)ws;                                   // 1152*384*2   = 884736 B
    u16* wp   = (u16*)(ws + 884736);                        // 384*384*2    = 294912 B
    u16* qkvb = (u16*)(ws + 1179648);                       // 231211008 B
    // xb aliases the attn-out buffer: xb is dead before attn_kernel writes it
    u16* xb   = (u16*)(ws + 232390656);                     // 77070336 B
    u16* attn = xb;

    prep_all<<<19104, 256, 0, stream>>>(x, qkv_w, proj_w, xb, wq, wp);
    qkv_gemm<<<7056, 256, 0, stream>>>(xb, wq, qkv_b, qkvb);
    attn_kernel<<<6144, 256, 0, stream>>>(qkvb, mask, attn);
    proj_gemm<<<2352, 256, 0, stream>>>(attn, wp, proj_b, out);
}

// Round 6
// 509.226 us; speedup vs baseline: 1.5656x; 1.5656x over previous
//
#include <hip/hip_runtime.h>
#include <hip/hip_bf16.h>
#include <stdint.h>

typedef unsigned short u16;
typedef __attribute__((ext_vector_type(8))) short short8;
typedef __attribute__((ext_vector_type(4))) short s4v;
typedef __attribute__((ext_vector_type(4))) float f32x4;

__device__ inline u16 f2bf(float f) {
    union { float f; unsigned int u; } x; x.f = f;
    unsigned int u = x.u;
    unsigned int r = (u + 0x7FFFu + ((u >> 16) & 1u)) >> 16;
    return (u16)r;
}

// async global->LDS, 16B per lane; LDS dest must be wave-uniform base (lane*16 implicit)
__device__ inline void gld_lds16(const u16* g, u16* l) {
    auto const* gp = reinterpret_cast<const __attribute__((address_space(1))) unsigned int*>(
        reinterpret_cast<uintptr_t>(g));
    auto* lp = reinterpret_cast<__attribute__((address_space(3))) unsigned int*>(
        reinterpret_cast<uintptr_t>(l));
    __builtin_amdgcn_global_load_lds(gp, lp, 16, 0, 0);
}

// 16x16x16 bf16 MFMA: prefer intrinsics (compiler-managed hazards); asm fallback carries
// explicit s_nop fences.
#if __has_builtin(__builtin_amdgcn_mfma_f32_16x16x16bf16_1k)
#define MFMA16(a, b, c) __builtin_amdgcn_mfma_f32_16x16x16bf16_1k((a), (b), (c), 0, 0, 0)
#elif __has_builtin(__builtin_amdgcn_mfma_f32_16x16x16_bf16)
#define MFMA16(a, b, c) __builtin_amdgcn_mfma_f32_16x16x16_bf16((a), (b), (c), 0, 0, 0)
#else
__device__ inline f32x4 mfma16_asm(s4v a, s4v b, f32x4 c) {
    asm volatile("s_nop 1\n\tv_mfma_f32_16x16x16_bf16 %0, %1, %2, %0\n\ts_nop 7\n\ts_nop 7"
                 : "+v"(c) : "v"(a), "v"(b));
    return c;
}
#define MFMA16(a, b, c) mfma16_asm((a), (b), (c))
#endif

// ---------------- prepass: x + weights -> bf16; wq rows reordered by head ------------
// wq' row layout: nrow = h*96 + sec*32 + d  (sec: 0=q,1=k,2=v), from orig sec*384+h*32+d.
#define NX8 4816896   // 100352*384/8
#define NQ8 55296     // 1152*384/8
#define NP8 18432     // 384*384/8
__global__ __launch_bounds__(256) void prep_all(const float* __restrict__ x,
                                                const float* __restrict__ qw,
                                                const float* __restrict__ pw,
                                                u16* __restrict__ xb,
                                                u16* __restrict__ wqr,
                                                u16* __restrict__ wp) {
    size_t i = (size_t)blockIdx.x * 256 + threadIdx.x;
    const float* src; u16* dst; size_t soff, doff;
    if (i < NX8) {
        src = x; dst = xb; soff = i; doff = i;
    } else if (i < NX8 + NQ8) {
        size_t off = i - NX8;                 // 8-elem chunk index in wq
        int orow = (int)(off / 48);           // 384/8 = 48 chunks per row
        int chunk = (int)(off - (size_t)orow * 48);
        int sec = orow / 384;
        int rem = orow - sec * 384;
        int hh = rem >> 5, d = rem & 31;
        int nrow = hh * 96 + sec * 32 + d;
        src = qw; dst = wqr; soff = off; doff = (size_t)nrow * 48 + chunk;
    } else {
        src = pw; dst = wp; soff = i - (NX8 + NQ8); doff = soff;
    }
    float4 v0 = ((const float4*)src)[soff * 2];
    float4 v1 = ((const float4*)src)[soff * 2 + 1];
    u16 h[8];
    h[0] = f2bf(v0.x); h[1] = f2bf(v0.y); h[2] = f2bf(v0.z); h[3] = f2bf(v0.w);
    h[4] = f2bf(v1.x); h[5] = f2bf(v1.y); h[6] = f2bf(v1.z); h[7] = f2bf(v1.w);
    *(uint4*)(dst + doff * 8) = *(const uint4*)h;
}

// ---------------- kernel 1: FUSED QKV-GEMM + windowed attention ----------------------
// Block = (2 windows: rows row0..row0+97, padded M=128) x (1 head: wq' rows h*96..+95).
// Phase 1: round-4 2-phase global_load_lds GEMM, acc[2][6] per wave (swapped-C: m=lane).
// Phase 2: epilogue writes Q,K -> LDS QK[128][68] (q scaled), V -> LDS Vt[32][132] (transposed).
// Phase 3: round-3 attention per window (2 waves/window, 2 q-tiles each), direct store.
// qkvb (226MB write + 231MB read) never touches HBM. Dead rows 98..127: q>=49 never
// stored, k>=49 masked to -1e30, garbage V killed by P=0. Last block's stage rows clamped.
__global__ __launch_bounds__(256, 3) void qkv_attn(const u16* __restrict__ xb,
                                                   const u16* __restrict__ wqr,
                                                   const float* __restrict__ bias,
                                                   const float* __restrict__ mask,
                                                   u16* __restrict__ aout) {
    __shared__ __align__(16) u16 lds[14336];   // 28KB union
    u16* Abuf[2] = { lds, lds + 4096 };        // [128][32] each
    u16* Bbuf[2] = { lds + 8192, lds + 11264 };// [96][32] each
    u16* QK = lds;                             // [128][68]: cols 0-31 q, 32-63 k
    u16* Vt = lds + 8704;                      // [32][132]: Vt[d][m]

    const int tid = threadIdx.x;
    const int wave = tid >> 6, lane = tid & 63;
    const int lr = lane >> 4, lc = lane & 15;
    const int lin = blockIdx.x;
    const int xcd = lin & 7;
    const int idx = lin >> 3;            // 0..1535
    const int h = idx % 12;
    const int mp = xcd * 128 + idx / 12; // 0..1023
    const int row0 = mp * 98;

    f32x4 acc[2][6] = {};

    const int srow = lane >> 2, scol = (lane & 3) * 8;
    // A: wave stages rows wave*32..+31 (2 instrs); row clamp keeps last block in-bounds
    const int ar0 = row0 + wave * 32 + srow;
    const int ar1 = (ar0 < 100351) ? ar0 : 100351;
    const int ar2 = (ar0 + 16 < 100351) ? ar0 + 16 : 100351;
    const u16* aSrc1 = xb + (size_t)ar1 * 384 + scol;
    const u16* aSrc2 = xb + (size_t)ar2 * 384 + scol;
    // B: wave stages rows wave*16..+15; waves 0,1 also rows 64+wave*16..+15
    const u16* bSrc = wqr + (size_t)(h * 96 + wave * 16 + srow) * 384 + scol;

    auto stage = [&](int k0, int buf) {
        gld_lds16(aSrc1 + k0, Abuf[buf] + wave * 1024);
        gld_lds16(aSrc2 + k0, Abuf[buf] + wave * 1024 + 512);
        gld_lds16(bSrc + k0, Bbuf[buf] + wave * 512);
        if (wave < 2)
            gld_lds16(bSrc + (size_t)64 * 384 + k0, Bbuf[buf] + 2048 + wave * 512);
    };
    auto compute = [&](int buf) {
        short8 af[2], bfr[6];
#pragma unroll
        for (int i = 0; i < 2; ++i)
            af[i] = *(const short8*)&Abuf[buf][(wave * 32 + i * 16 + lc) * 32 + lr * 8];
#pragma unroll
        for (int j = 0; j < 6; ++j)
            bfr[j] = *(const short8*)&Bbuf[buf][(j * 16 + lc) * 32 + lr * 8];
#pragma unroll
        for (int i = 0; i < 2; ++i)
#pragma unroll
            for (int j = 0; j < 6; ++j)
                acc[i][j] = __builtin_amdgcn_mfma_f32_16x16x32_bf16(bfr[j], af[i], acc[i][j], 0, 0, 0);
    };

    stage(0, 0);
    __syncthreads();
#pragma unroll
    for (int t = 0; t < 12; ++t) {
        if (t < 11) stage((t + 1) * 32, (t + 1) & 1);
        compute(t & 1);
        __syncthreads();   // also serves as the staging-LDS -> QK/Vt union barrier at t=11
    }

    // ---- epilogue: acc -> LDS. mapping: m = wave*32+i*16+lc, n' = j*16+lr*4+r ----
    const float scale = 0.17677669529663687f;  // 32^-0.5
#pragma unroll
    for (int j = 0; j < 6; ++j) {
        const int sec = j >> 1;                    // 0=q,1=k,2=v
        const int nb = (j & 1) * 16 + lr * 4;      // 0..28 within the 32-col section
        float4 bv = *(const float4*)&bias[sec * 384 + h * 32 + nb];
        const float mult = (sec == 0) ? scale : 1.0f;
#pragma unroll
        for (int i = 0; i < 2; ++i) {
            const int m = wave * 32 + i * 16 + lc;
            float v0 = (acc[i][j][0] + bv.x) * mult;
            float v1 = (acc[i][j][1] + bv.y) * mult;
            float v2 = (acc[i][j][2] + bv.z) * mult;
            float v3 = (acc[i][j][3] + bv.w) * mult;
            if (sec < 2) {
                union { u16 h[4]; uint2 u; } pk;
                pk.h[0] = f2bf(v0); pk.h[1] = f2bf(v1);
                pk.h[2] = f2bf(v2); pk.h[3] = f2bf(v3);
                *(uint2*)&QK[m * 68 + sec * 32 + nb] = pk.u;
            } else {
                Vt[(nb + 0) * 132 + m] = f2bf(v0);
                Vt[(nb + 1) * 132 + m] = f2bf(v1);
                Vt[(nb + 2) * 132 + m] = f2bf(v2);
                Vt[(nb + 3) * 132 + m] = f2bf(v3);
            }
        }
    }
    __syncthreads();

    // ---- attention: 2 waves per window, 2 q-tiles per wave (round-3 math) ----
    const int winSel = wave & 1, qh = wave >> 1;
    const int woff = winSel * 49;
    const float* mrow = mask + (size_t)((2 * mp + winSel) & 63) * 2401;

    short8 kf[4], qf[2];
    s4v vfA[2][4];
#pragma unroll
    for (int j = 0; j < 4; ++j)
        kf[j] = *(const short8*)&QK[(woff + j * 16 + lc) * 68 + 32 + lr * 8];
#pragma unroll
    for (int ii = 0; ii < 2; ++ii)
        qf[ii] = *(const short8*)&QK[(woff + (qh * 2 + ii) * 16 + lc) * 68 + lr * 8];
#pragma unroll
    for (int nt = 0; nt < 2; ++nt)
#pragma unroll
        for (int sj = 0; sj < 4; ++sj)
            vfA[nt][sj] = *(const s4v*)&Vt[(nt * 16 + lc) * 132 + woff + sj * 16 + lr * 4];

    // S2 = K Q^T (swapped): reg r of (ii,sj) holds S[k=sj*16+lr*4+r][q=(qh*2+ii)*16+lc]
    f32x4 S2[2][4] = {};
#pragma unroll
    for (int ii = 0; ii < 2; ++ii)
#pragma unroll
        for (int sj = 0; sj < 4; ++sj)
            S2[ii][sj] = __builtin_amdgcn_mfma_f32_16x16x32_bf16(kf[sj], qf[ii], S2[ii][sj], 0, 0, 0);

    const size_t orow = (size_t)(row0 + woff) * 384 + h * 32 + lr * 4;
#pragma unroll
    for (int ii = 0; ii < 2; ++ii) {
        const int q = (qh * 2 + ii) * 16 + lc;
        const int im = (q < 49) ? q : 48;
        const float* mq = mrow + im * 49;
        float s = 0.0f;
        s4v pfq[4];
#pragma unroll
        for (int sj = 0; sj < 4; ++sj) {
            const int kbase = sj * 16 + lr * 4;
            s4v pk;
#pragma unroll
            for (int r = 0; r < 4; ++r) {
                const int k = kbase + r;
                float t = (k < 49) ? (S2[ii][sj][r] + mq[k]) : -1e30f;
                float p = __expf(t);
                s += p;
                pk[r] = (short)f2bf(p);
            }
            pfq[sj] = pk;
        }
        s += __shfl_xor(s, 16);
        s += __shfl_xor(s, 32);

        f32x4 O0 = {}, O1 = {};
#pragma unroll
        for (int sj = 0; sj < 4; ++sj) {
            O0 = MFMA16(vfA[0][sj], pfq[sj], O0);
            O1 = MFMA16(vfA[1][sj], pfq[sj], O1);
        }

        if (q < 49) {
            float rl = __builtin_amdgcn_rcpf(s);
            union { u16 h[4]; uint2 u; } pk;
            pk.h[0] = f2bf(O0[0] * rl); pk.h[1] = f2bf(O0[1] * rl);
            pk.h[2] = f2bf(O0[2] * rl); pk.h[3] = f2bf(O0[3] * rl);
            *(uint2*)(aout + orow + (size_t)q * 384) = pk.u;
            pk.h[0] = f2bf(O1[0] * rl); pk.h[1] = f2bf(O1[1] * rl);
            pk.h[2] = f2bf(O1[2] * rl); pk.h[3] = f2bf(O1[3] * rl);
            *(uint2*)(aout + orow + (size_t)q * 384 + 16) = pk.u;
        }
    }
}

// ---------------- kernel 3: proj GEMM (verified round-4 2-phase version) --------------
__global__ __launch_bounds__(256) void proj_gemm(const u16* __restrict__ a,
                                                 const u16* __restrict__ wp,
                                                 const float* __restrict__ bias,
                                                 float* __restrict__ out) {
    __shared__ u16 As[2][128 * 32];
    __shared__ u16 Bs[2][128 * 32];
    const int tid = threadIdx.x;
    const int wave = tid >> 6, lane = tid & 63;
    const int lr = lane >> 4, lc = lane & 15;
    const int wm = (wave & 1) * 64, wn = (wave >> 1) * 64;
    const int lin = blockIdx.x;
    const int xcd = lin & 7;
    const int idx = lin >> 3;            // 0..293
    const int nBase = (idx % 3) * 128;
    const int mBase = (xcd * 98 + idx / 3) * 128;

    f32x4 acc[4][4] = {};

    const int srow = lane >> 2, scol = (lane & 3) * 8;
    const u16* aSrc = a  + (size_t)(mBase + wave * 32 + srow) * 384 + scol;
    const u16* bSrc = wp + (size_t)(nBase + wave * 32 + srow) * 384 + scol;

    auto stage = [&](int k0, int buf) {
        u16* aDst = &As[buf][wave * 1024];
        u16* bDst = &Bs[buf][wave * 1024];
        gld_lds16(aSrc + k0, aDst);
        gld_lds16(aSrc + k0 + (size_t)16 * 384, aDst + 512);
        gld_lds16(bSrc + k0, bDst);
        gld_lds16(bSrc + k0 + (size_t)16 * 384, bDst + 512);
    };
    auto compute = [&](int buf) {
        short8 af[4], bfr[4];
#pragma unroll
        for (int i = 0; i < 4; ++i)
            af[i] = *(const short8*)&As[buf][(wm + i * 16 + lc) * 32 + lr * 8];
#pragma unroll
        for (int j = 0; j < 4; ++j)
            bfr[j] = *(const short8*)&Bs[buf][(wn + j * 16 + lc) * 32 + lr * 8];
#pragma unroll
        for (int i = 0; i < 4; ++i)
#pragma unroll
            for (int j = 0; j < 4; ++j)
                acc[i][j] = __builtin_amdgcn_mfma_f32_16x16x32_bf16(bfr[j], af[i], acc[i][j], 0, 0, 0);
    };

    stage(0, 0);
    __syncthreads();
#pragma unroll
    for (int t = 0; t < 11; ++t) {
        stage((t + 1) * 32, (t + 1) & 1);
        compute(t & 1);
        __syncthreads();
    }
    compute(11 & 1);

    // epilogue: swapped-C mapping: m = wm+i*16+lc (lane), n = wn+j*16+lr*4+r (reg)
#pragma unroll
    for (int j = 0; j < 4; ++j) {
        int gnb = nBase + wn + j * 16 + lr * 4;
        float4 bv = *(const float4*)&bias[gnb];
#pragma unroll
        for (int i = 0; i < 4; ++i) {
            int gm = mBase + wm + i * 16 + lc;
            float4 o;
            o.x = acc[i][j][0] + bv.x;
            o.y = acc[i][j][1] + bv.y;
            o.z = acc[i][j][2] + bv.z;
            o.w = acc[i][j][3] + bv.w;
            *(float4*)(out + (size_t)gm * 384 + gnb) = o;
        }
    }
}

// ---------------- launch ----------------
extern "C" void kernel_launch(void* const* d_in, const int* in_sizes, int n_in,
                              void* d_out, int out_size, void* d_ws, size_t ws_size,
                              hipStream_t stream) {
    const float* x      = (const float*)d_in[0];
    const float* mask   = (const float*)d_in[1];
    const float* qkv_w  = (const float*)d_in[2];
    const float* qkv_b  = (const float*)d_in[3];
    const float* proj_w = (const float*)d_in[4];
    const float* proj_b = (const float*)d_in[5];
    float* out = (float*)d_out;

    char* ws = (char*)d_ws;
    u16* wqr  = (u16*)ws;                                   // 1152*384*2 = 884736 B (head-reordered)
    u16* wp   = (u16*)(ws + 884736);                        // 384*384*2  = 294912 B
    u16* attn = (u16*)(ws + 1179648);                       // 77070336 B (attn out, old qkvb slot)
    u16* xb   = (u16*)(ws + 232390656);                     // 77070336 B

    prep_all<<<19104, 256, 0, stream>>>(x, qkv_w, proj_w, xb, wqr, wp);
    qkv_attn<<<12288, 256, 0, stream>>>(xb, wqr, qkv_b, mask, attn);
    proj_gemm<<<2352, 256, 0, stream>>>(attn, wp, proj_b, out);
}